// Round 1
// 432.418 us; speedup vs baseline: 1.0476x; 1.0476x over previous
//
#include <hip/hip_runtime.h>
#include <math.h>

#define D_INNER 8192
#define D_MODEL 4096
#define DT_RANK 8
#define D_STATE 16

typedef float f32x4 __attribute__((ext_vector_type(4)));

__device__ __forceinline__ float dot4(f32x4 a, f32x4 b) {
  return a.x * b.x + a.y * b.y + a.z * b.z + a.w * b.w;
}

// ---------------------------------------------------------------------------
// K1: xz = W_in @ x  (16384 rows x 4096 cols). One wave per row, 4 waves per
// block. Weight rows are streamed with nontemporal loads (zero reuse) so the
// shared x vector stays resident in L1/L2. Epilogue fuses depthwise conv +
// SiLU (x branch) / SiLU (z branch).
// ---------------------------------------------------------------------------
__global__ __launch_bounds__(256) void gemv_in_kernel(
    const float* __restrict__ W_in, const float* __restrict__ x,
    const float* __restrict__ conv_buffer, const float* __restrict__ conv_w,
    const float* __restrict__ conv_b,
    float* __restrict__ x_conv, float* __restrict__ silu_z) {
  const int wave = threadIdx.x >> 6;
  const int lane = threadIdx.x & 63;
  const int row = blockIdx.x * 4 + wave;            // grid = 4096 blocks
  const f32x4* __restrict__ Wr = (const f32x4*)(W_in + (size_t)row * D_MODEL);
  const f32x4* __restrict__ x4 = (const f32x4*)x;

  float acc = 0.f;
#pragma unroll 8
  for (int it = 0; it < 16; ++it) {                 // 1024 float4 / 64 lanes
    f32x4 w = __builtin_nontemporal_load(&Wr[lane + it * 64]);
    f32x4 v = x4[lane + it * 64];
    acc += dot4(w, v);
  }
#pragma unroll
  for (int off = 32; off; off >>= 1) acc += __shfl_down(acc, off, 64);

  if (lane == 0) {
    if (row < D_INNER) {
      // conv_in = [buf1, buf2, xb, xb] . conv_w + conv_b, then SiLU
      float pre = conv_buffer[row * 3 + 1] * conv_w[row * 4 + 0]
                + conv_buffer[row * 3 + 2] * conv_w[row * 4 + 1]
                + acc * (conv_w[row * 4 + 2] + conv_w[row * 4 + 3])
                + conv_b[row];
      x_conv[row] = pre / (1.f + __expf(-pre));
    } else {
      const int i = row - D_INNER;
      silu_z[i] = acc / (1.f + __expf(-acc));
    }
  }
}

// ---------------------------------------------------------------------------
// K2: xp = W_xp @ x_conv  (40 rows x 8192 cols), split-K for parallelism.
// grid = 40 rows x 8 chunks = 320 blocks; each block reduces a 1024-element
// chunk (1 float4/thread) and writes a deterministic partial. The final 8-way
// sum is folded into K3's prologue.
// ---------------------------------------------------------------------------
__global__ __launch_bounds__(256) void gemv_xp_kernel(
    const float* __restrict__ W_xp, const float* __restrict__ x_conv,
    float* __restrict__ xp_part) {
  const int j = blockIdx.x >> 3;                    // row 0..39
  const int c = blockIdx.x & 7;                     // chunk 0..7
  const f32x4* __restrict__ Wr  = (const f32x4*)(W_xp + (size_t)j * D_INNER + c * 1024);
  const f32x4* __restrict__ xc4 = (const f32x4*)(x_conv + c * 1024);

  float acc = dot4(Wr[threadIdx.x], xc4[threadIdx.x]);
#pragma unroll
  for (int off = 32; off; off >>= 1) acc += __shfl_down(acc, off, 64);

  __shared__ float part[4];
  if ((threadIdx.x & 63) == 0) part[threadIdx.x >> 6] = acc;
  __syncthreads();
  if (threadIdx.x == 0) xp_part[blockIdx.x] = part[0] + part[1] + part[2] + part[3];
}

// ---------------------------------------------------------------------------
// K3: per-channel SSM cell, 4 threads per row (each owns 4 states) so that
// A_log / ssm_state / new_h move as coalesced float4. Prologue reduces the
// split-K partials into xp in LDS. dt is computed redundantly per thread-quad
// (8 FMAs from LDS); y reduced across the quad with 2 shuffles.
// ---------------------------------------------------------------------------
__global__ __launch_bounds__(256) void cell_kernel(
    const float* __restrict__ W_dt, const float* __restrict__ b_dt,
    const float* __restrict__ A_log, const float* __restrict__ ssm_state,
    const float* __restrict__ D_param, const float* __restrict__ x_conv,
    const float* __restrict__ silu_z, const float* __restrict__ xp_part,
    float* __restrict__ new_h, float* __restrict__ y) {
  __shared__ float xp_s[DT_RANK + 2 * D_STATE];
  if (threadIdx.x < DT_RANK + 2 * D_STATE) {
    float s = 0.f;
#pragma unroll
    for (int c = 0; c < 8; ++c) s += xp_part[threadIdx.x * 8 + c];
    xp_s[threadIdx.x] = s;
  }
  __syncthreads();

  const int t  = blockIdx.x * 256 + threadIdx.x;    // grid = 128 blocks
  const int i  = t >> 2;                            // row 0..8191
  const int sq = (t & 3) << 2;                      // state quad base 0/4/8/12

  const f32x4 wd0 = *(const f32x4*)(W_dt + i * DT_RANK);
  const f32x4 wd1 = *(const f32x4*)(W_dt + i * DT_RANK + 4);
  float d = b_dt[i]
          + wd0.x * xp_s[0] + wd0.y * xp_s[1] + wd0.z * xp_s[2] + wd0.w * xp_s[3]
          + wd1.x * xp_s[4] + wd1.y * xp_s[5] + wd1.z * xp_s[6] + wd1.w * xp_s[7];
  const float dt = (d > 20.f) ? d : log1pf(__expf(d));   // stable softplus
  const float xc = x_conv[i];

  const f32x4 al = *(const f32x4*)(A_log + i * D_STATE + sq);
  const f32x4 h0 = *(const f32x4*)(ssm_state + i * D_STATE + sq);
  f32x4 h;
  float y_acc = 0.f;
#pragma unroll
  for (int s = 0; s < 4; ++s) {
    const float A    = -__expf(al[s]);
    const float Abar = __expf(dt * A);
    const float hv   = Abar * h0[s] + dt * xp_s[DT_RANK + sq + s] * xc;
    h[s] = hv;
    y_acc += hv * xp_s[DT_RANK + D_STATE + sq + s];
  }
  *(f32x4*)(new_h + i * D_STATE + sq) = h;

  y_acc += __shfl_down(y_acc, 1, 64);
  y_acc += __shfl_down(y_acc, 2, 64);
  if ((t & 3) == 0) y[i] = (y_acc + D_param[i] * xc) * silu_z[i];
}

// ---------------------------------------------------------------------------
// K4: out = W_out @ y  (4096 rows x 8192 cols). One wave per row, streamed
// weight rows via nontemporal loads; y stays cached.
// ---------------------------------------------------------------------------
__global__ __launch_bounds__(256) void gemv_out_kernel(
    const float* __restrict__ W_out, const float* __restrict__ y,
    float* __restrict__ out) {
  const int wave = threadIdx.x >> 6;
  const int lane = threadIdx.x & 63;
  const int row = blockIdx.x * 4 + wave;            // grid = 1024 blocks
  const f32x4* __restrict__ Wr = (const f32x4*)(W_out + (size_t)row * D_INNER);
  const f32x4* __restrict__ y4 = (const f32x4*)y;

  float acc = 0.f;
#pragma unroll 8
  for (int it = 0; it < 32; ++it) {                 // 2048 float4 / 64 lanes
    f32x4 w = __builtin_nontemporal_load(&Wr[lane + it * 64]);
    f32x4 v = y4[lane + it * 64];
    acc += dot4(w, v);
  }
#pragma unroll
  for (int off = 32; off; off >>= 1) acc += __shfl_down(acc, off, 64);
  if (lane == 0) out[row] = acc;
}

extern "C" void kernel_launch(void* const* d_in, const int* in_sizes, int n_in,
                              void* d_out, int out_size, void* d_ws, size_t ws_size,
                              hipStream_t stream) {
  const float* x           = (const float*)d_in[0];
  const float* ssm_state   = (const float*)d_in[1];
  const float* conv_buffer = (const float*)d_in[2];
  const float* W_in        = (const float*)d_in[3];
  const float* conv_w      = (const float*)d_in[4];
  const float* conv_b      = (const float*)d_in[5];
  const float* W_xp        = (const float*)d_in[6];
  const float* W_dt        = (const float*)d_in[7];
  const float* b_dt        = (const float*)d_in[8];
  const float* A_log       = (const float*)d_in[9];
  const float* D_param     = (const float*)d_in[10];
  const float* W_out       = (const float*)d_in[11];

  float* out   = (float*)d_out;            // [0, 4096): out
  float* new_h = (float*)d_out + D_MODEL;  // [4096, 4096+131072): new_h

  float* ws      = (float*)d_ws;
  float* x_conv  = ws;                     // 8192
  float* silu_z  = ws + 8192;              // 8192
  float* xp_part = ws + 16384;             // 320 (40 rows x 8 chunks)
  float* y       = ws + 16704;             // 8192

  gemv_in_kernel<<<(2 * D_INNER) / 4, 256, 0, stream>>>(
      W_in, x, conv_buffer, conv_w, conv_b, x_conv, silu_z);
  gemv_xp_kernel<<<(DT_RANK + 2 * D_STATE) * 8, 256, 0, stream>>>(
      W_xp, x_conv, xp_part);
  cell_kernel<<<(D_INNER * 4) / 256, 256, 0, stream>>>(
      W_dt, b_dt, A_log, ssm_state, D_param, x_conv, silu_z, xp_part, new_h, y);
  gemv_out_kernel<<<D_MODEL / 4, 256, 0, stream>>>(W_out, y, out);
}